// Round 1
// baseline (11149.031 us; speedup 1.0000x reference)
//
#include <hip/hip_runtime.h>

// RNN_90829968376262 — Round 1: correct all-fp32 baseline.
// T=256, B=256, V=512, H=1024.
// d_ws layout: buf = float[T*B*H] (256 MB). Phase 1 writes xh into buf;
// the scan overwrites buf[t] in place with h_t = tanh(xh_t + h_{t-1}@W_hh);
// phase 3 reads buf as hs. Final state = buf[T-1].

#define T_STEPS 256
#define B_SZ    256
#define V_SZ    512
#define H_SZ    1024

// ---------- generic 64x64-tile fp32 GEMM: C = A[MxK]*Bw[KxN] + bias ----------
__global__ __launch_bounds__(256)
void gemm_bias(const float* __restrict__ A, const float* __restrict__ Bw,
               const float* __restrict__ bias, float* __restrict__ C,
               int M, int N, int K)
{
    __shared__ __align__(16) float As[16][64];   // [k][m] (transposed tile)
    __shared__ __align__(16) float Bs[16][64];   // [k][n]
    const int tid = threadIdx.x;
    const int tx = tid & 15, ty = tid >> 4;
    const int row0 = blockIdx.y * 64, col0 = blockIdx.x * 64;

    // loader lanes
    const int la_r = tid >> 2;          // 0..63  row within A tile
    const int la_k = (tid & 3) << 2;    // 0,4,8,12  k within chunk (float4)
    const int lb_k = tid >> 4;          // 0..15
    const int lb_c = (tid & 15) << 2;   // col within tile (float4)

    float acc[4][4] = {};

    for (int kc = 0; kc < K; kc += 16) {
        float4 a4 = *reinterpret_cast<const float4*>(
            A + (size_t)(row0 + la_r) * K + kc + la_k);
        float4 b4 = *reinterpret_cast<const float4*>(
            Bw + (size_t)(kc + lb_k) * N + col0 + lb_c);
        __syncthreads();
        As[la_k + 0][la_r] = a4.x;
        As[la_k + 1][la_r] = a4.y;
        As[la_k + 2][la_r] = a4.z;
        As[la_k + 3][la_r] = a4.w;
        *reinterpret_cast<float4*>(&Bs[lb_k][lb_c]) = b4;
        __syncthreads();
#pragma unroll
        for (int kk = 0; kk < 16; ++kk) {
            float4 ra = *reinterpret_cast<const float4*>(&As[kk][ty << 2]);
            float4 rb = *reinterpret_cast<const float4*>(&Bs[kk][tx << 2]);
            acc[0][0] += ra.x * rb.x; acc[0][1] += ra.x * rb.y;
            acc[0][2] += ra.x * rb.z; acc[0][3] += ra.x * rb.w;
            acc[1][0] += ra.y * rb.x; acc[1][1] += ra.y * rb.y;
            acc[1][2] += ra.y * rb.z; acc[1][3] += ra.y * rb.w;
            acc[2][0] += ra.z * rb.x; acc[2][1] += ra.z * rb.y;
            acc[2][2] += ra.z * rb.z; acc[2][3] += ra.z * rb.w;
            acc[3][0] += ra.w * rb.x; acc[3][1] += ra.w * rb.y;
            acc[3][2] += ra.w * rb.z; acc[3][3] += ra.w * rb.w;
        }
    }

    const int cb = col0 + (tx << 2);
    float4 bv = *reinterpret_cast<const float4*>(bias + cb);
#pragma unroll
    for (int i = 0; i < 4; ++i) {
        float4 o;
        o.x = acc[i][0] + bv.x;
        o.y = acc[i][1] + bv.y;
        o.z = acc[i][2] + bv.z;
        o.w = acc[i][3] + bv.w;
        *reinterpret_cast<float4*>(
            C + (size_t)(row0 + (ty << 2) + i) * N + cb) = o;
    }
}

// ---------- RNN step: XH[r][c] = tanh(XH[r][c] + (Hprev @ Whh)[r][c]) --------
// M=256 (B), N=1024 (H), K=1024.  Tile 16x64, grid (16,16)=256 blocks.
__global__ __launch_bounds__(256)
void rnn_step(const float* __restrict__ Hprev, const float* __restrict__ Whh,
              float* __restrict__ XH)
{
    __shared__ __align__(16) float As[16][16];   // [k][m]
    __shared__ __align__(16) float Bs[16][64];   // [k][n]
    const int tid = threadIdx.x;
    const int tx = tid & 15, ty = tid >> 4;
    const int row0 = blockIdx.y * 16, col0 = blockIdx.x * 64;

    const int la_m = tid >> 4;        // 0..15 row
    const int la_k = tid & 15;        // 0..15 k
    const int lb_k = tid >> 4;
    const int lb_c = (tid & 15) << 2;

    float acc[4] = {0.f, 0.f, 0.f, 0.f};

    for (int kc = 0; kc < H_SZ; kc += 16) {
        float a = Hprev[(size_t)(row0 + la_m) * H_SZ + kc + la_k];
        float4 b4 = *reinterpret_cast<const float4*>(
            Whh + (size_t)(kc + lb_k) * H_SZ + col0 + lb_c);
        __syncthreads();
        As[la_k][la_m] = a;
        *reinterpret_cast<float4*>(&Bs[lb_k][lb_c]) = b4;
        __syncthreads();
#pragma unroll
        for (int kk = 0; kk < 16; ++kk) {
            float ra = As[kk][ty];
            float4 rb = *reinterpret_cast<const float4*>(&Bs[kk][tx << 2]);
            acc[0] += ra * rb.x;
            acc[1] += ra * rb.y;
            acc[2] += ra * rb.z;
            acc[3] += ra * rb.w;
        }
    }

    float* px = XH + (size_t)(row0 + ty) * H_SZ + col0 + (tx << 2);
    float4 x = *reinterpret_cast<const float4*>(px);
    float4 o;
    o.x = tanhf(x.x + acc[0]);
    o.y = tanhf(x.y + acc[1]);
    o.z = tanhf(x.z + acc[2]);
    o.w = tanhf(x.w + acc[3]);
    *reinterpret_cast<float4*>(px) = o;
}

// ---------- t=0: buf[0] = tanh(buf[0])  (h0 == 0) ----------
__global__ __launch_bounds__(256)
void tanh_inplace(float* __restrict__ X, int n)
{
    int i = (blockIdx.x * 256 + threadIdx.x) * 4;
    if (i < n) {
        float4 x = *reinterpret_cast<float4*>(X + i);
        float4 o;
        o.x = tanhf(x.x); o.y = tanhf(x.y); o.z = tanhf(x.z); o.w = tanhf(x.w);
        *reinterpret_cast<float4*>(X + i) = o;
    }
}

// ---------- copy final state into output tail ----------
__global__ __launch_bounds__(256)
void copy_f4(const float* __restrict__ src, float* __restrict__ dst, int n4)
{
    int i = blockIdx.x * 256 + threadIdx.x;
    if (i < n4) {
        reinterpret_cast<float4*>(dst)[i] =
            reinterpret_cast<const float4*>(src)[i];
    }
}

extern "C" void kernel_launch(void* const* d_in, const int* in_sizes, int n_in,
                              void* d_out, int out_size, void* d_ws, size_t ws_size,
                              hipStream_t stream)
{
    const float* inputs  = (const float*)d_in[0];  // [T,B,V]
    const float* W_xh    = (const float*)d_in[1];  // [V,H]
    const float* W_hh    = (const float*)d_in[2];  // [H,H]
    const float* b_h     = (const float*)d_in[3];  // [H]
    const float* W_dense = (const float*)d_in[4];  // [H,V]
    const float* b_dense = (const float*)d_in[5];  // [V]
    float* out = (float*)d_out;

    float* buf = (float*)d_ws;                     // T*B*H floats = 256 MB
    const int M1 = T_STEPS * B_SZ;                 // 65536
    const size_t BH = (size_t)B_SZ * H_SZ;         // 262144

    // Phase 1: xh = inputs @ W_xh + b_h   -> buf
    gemm_bias<<<dim3(H_SZ / 64, M1 / 64), 256, 0, stream>>>(
        inputs, W_xh, b_h, buf, M1, H_SZ, V_SZ);

    // t = 0: h0 = 0 -> buf[0] = tanh(buf[0])
    tanh_inplace<<<dim3((int)(BH / 1024)), 256, 0, stream>>>(buf, (int)BH);

    // Phase 2: sequential scan, in-place over buf[t]
    for (int t = 1; t < T_STEPS; ++t) {
        rnn_step<<<dim3(H_SZ / 64, B_SZ / 16), 256, 0, stream>>>(
            buf + (size_t)(t - 1) * BH, W_hh, buf + (size_t)t * BH);
    }

    // Phase 3: outputs = hs @ W_dense + b_dense   -> out
    gemm_bias<<<dim3(V_SZ / 64, M1 / 64), 256, 0, stream>>>(
        buf, W_dense, b_dense, out, M1, V_SZ, H_SZ);

    // Final state -> out tail
    copy_f4<<<dim3((int)(BH / 1024)), 256, 0, stream>>>(
        buf + (size_t)(T_STEPS - 1) * BH, out + (size_t)M1 * V_SZ, (int)(BH / 4));
}

// Round 2
// 5460.173 us; speedup vs baseline: 2.0419x; 2.0419x over previous
//
#include <hip/hip_runtime.h>

// RNN_90829968376262 — Round 2.
// Numerics strategy (from round-1 evidence): the recurrence amplifies per-step
// noise by ~1e4, so phase 1 and the scan stay fp32; only phase 3 (direct
// output, no amplification) uses bf16 MFMA.
// Memory plan: buf = d_ws (256 MB): xh[t] overwritten in place by h_t (fp32).
//   P (8 MB K-split partials) = start of d_out (overwritten by phase 3 later).
//   WdT (1 MB bf16 transposed W_dense) = tail of d_out (final-state region,
//   overwritten only by the last copy kernel).

#define T_STEPS 256
#define B_SZ    256
#define V_SZ    512
#define H_SZ    1024
#define BH      (B_SZ * H_SZ)          // 262144
#define M1      (T_STEPS * B_SZ)       // 65536

typedef __attribute__((ext_vector_type(8))) short bf16x8;
typedef __attribute__((ext_vector_type(4))) float f32x4;

// round-to-nearest-even fp32 -> bf16 bit pattern
__device__ inline unsigned short bf16_rne(float f) {
    unsigned u = __float_as_uint(f);
    u += 0x7fffu + ((u >> 16) & 1u);
    return (unsigned short)(u >> 16);
}

// =====================  Phase 1: fp32 GEMM 128x128 tile =====================
// C[M1 x H] = A[M1 x V] * B[V x H] + bias   (M1=65536, V=512, H=1024)
__global__ __launch_bounds__(256, 4)
void gemm_f32_xh(const float* __restrict__ A, const float* __restrict__ Bw,
                 const float* __restrict__ bias, float* __restrict__ C)
{
    __shared__ __align__(16) float As[16][128];   // [k][m]
    __shared__ __align__(16) float Bs[16][128];   // [k][n]
    const int tid = threadIdx.x;
    const int tx = tid & 15, ty = tid >> 4;
    const int r0 = blockIdx.y * 128, c0 = blockIdx.x * 128;
    const int ar = tid >> 1, ak = (tid & 1) * 8;     // A loader: row, k-offset
    const int bk = tid >> 4, bc = (tid & 15) * 8;    // B loader

    float acc[8][8] = {};

    for (int kc = 0; kc < V_SZ; kc += 16) {
        const float* ap = A + (size_t)(r0 + ar) * V_SZ + kc + ak;
        float4 a0 = ((const float4*)ap)[0];
        float4 a1 = ((const float4*)ap)[1];
        const float* bp = Bw + (size_t)(kc + bk) * H_SZ + c0 + bc;
        float4 b0 = ((const float4*)bp)[0];
        float4 b1 = ((const float4*)bp)[1];
        __syncthreads();
        As[ak + 0][ar] = a0.x; As[ak + 1][ar] = a0.y;
        As[ak + 2][ar] = a0.z; As[ak + 3][ar] = a0.w;
        As[ak + 4][ar] = a1.x; As[ak + 5][ar] = a1.y;
        As[ak + 6][ar] = a1.z; As[ak + 7][ar] = a1.w;
        *(float4*)&Bs[bk][bc]     = b0;
        *(float4*)&Bs[bk][bc + 4] = b1;
        __syncthreads();
#pragma unroll
        for (int kk = 0; kk < 16; ++kk) {
            float ra[8], rb[8];
            *(float4*)(ra)     = *(const float4*)&As[kk][ty * 8];
            *(float4*)(ra + 4) = *(const float4*)&As[kk][ty * 8 + 4];
            *(float4*)(rb)     = *(const float4*)&Bs[kk][tx * 8];
            *(float4*)(rb + 4) = *(const float4*)&Bs[kk][tx * 8 + 4];
#pragma unroll
            for (int i = 0; i < 8; ++i)
#pragma unroll
                for (int j = 0; j < 8; ++j)
                    acc[i][j] += ra[i] * rb[j];
        }
    }

    float4 bv0 = *(const float4*)(bias + c0 + tx * 8);
    float4 bv1 = *(const float4*)(bias + c0 + tx * 8 + 4);
#pragma unroll
    for (int i = 0; i < 8; ++i) {
        float* cp = C + (size_t)(r0 + ty * 8 + i) * H_SZ + c0 + tx * 8;
        float4 o0, o1;
        o0.x = acc[i][0] + bv0.x; o0.y = acc[i][1] + bv0.y;
        o0.z = acc[i][2] + bv0.z; o0.w = acc[i][3] + bv0.w;
        o1.x = acc[i][4] + bv1.x; o1.y = acc[i][5] + bv1.y;
        o1.z = acc[i][6] + bv1.z; o1.w = acc[i][7] + bv1.w;
        ((float4*)cp)[0] = o0;
        ((float4*)cp)[1] = o1;
    }
}

// =====================  Scan step: K-split fp32 GEMM =====================
// Partial[ks] (64x128 tile) = Hprev[64 x 128k-slice] @ Whh[128k x 128n]
// grid (8 colblk, 4 rowblk, 8 ksplit) = 256 blocks, 512 threads.
__global__ __launch_bounds__(512, 2)
void scan_gemm(const float* __restrict__ Hprev, const float* __restrict__ Whh,
               float* __restrict__ P)
{
    __shared__ __align__(16) float As[16][68];    // [k][m], padded stride
    __shared__ __align__(16) float Bs[16][128];   // [k][n]
    const int tid = threadIdx.x;
    const int tx = tid & 31, ty = tid >> 5;       // micro: 4 cols x 4 rows
    const int c0 = blockIdx.x * 128;
    const int r0 = blockIdx.y * 64;
    const int k0 = blockIdx.z * 128;
    const int ar = tid >> 3, ak = (tid & 7) * 2;  // A loader (float2 along k)
    const int bk = tid >> 5, bc = (tid & 31) * 4; // B loader (float4)

    float acc[4][4] = {};

    for (int kc = 0; kc < 128; kc += 16) {
        float2 a2 = *(const float2*)(Hprev + (size_t)(r0 + ar) * H_SZ + k0 + kc + ak);
        float4 b4 = *(const float4*)(Whh + (size_t)(k0 + kc + bk) * H_SZ + c0 + bc);
        __syncthreads();
        As[ak][ar]     = a2.x;
        As[ak + 1][ar] = a2.y;
        *(float4*)&Bs[bk][bc] = b4;
        __syncthreads();
#pragma unroll
        for (int kk = 0; kk < 16; ++kk) {
            float4 ra = *(const float4*)&As[kk][ty * 4];
            float4 rb = *(const float4*)&Bs[kk][tx * 4];
            acc[0][0] += ra.x * rb.x; acc[0][1] += ra.x * rb.y;
            acc[0][2] += ra.x * rb.z; acc[0][3] += ra.x * rb.w;
            acc[1][0] += ra.y * rb.x; acc[1][1] += ra.y * rb.y;
            acc[1][2] += ra.y * rb.z; acc[1][3] += ra.y * rb.w;
            acc[2][0] += ra.z * rb.x; acc[2][1] += ra.z * rb.y;
            acc[2][2] += ra.z * rb.z; acc[2][3] += ra.z * rb.w;
            acc[3][0] += ra.w * rb.x; acc[3][1] += ra.w * rb.y;
            acc[3][2] += ra.w * rb.z; acc[3][3] += ra.w * rb.w;
        }
    }

    float* pp = P + (size_t)blockIdx.z * BH;
#pragma unroll
    for (int i = 0; i < 4; ++i) {
        float4 o; o.x = acc[i][0]; o.y = acc[i][1]; o.z = acc[i][2]; o.w = acc[i][3];
        *(float4*)(pp + (size_t)(r0 + ty * 4 + i) * H_SZ + c0 + tx * 4) = o;
    }
}

// reduce 8 partials + xh, tanh, write h_t in place over xh[t]
__global__ __launch_bounds__(256)
void scan_reduce(const float* __restrict__ P, float* __restrict__ XH)
{
    int i = (blockIdx.x * 256 + threadIdx.x) * 4;
    float4 s = *(const float4*)(XH + i);
#pragma unroll
    for (int ks = 0; ks < 8; ++ks) {
        float4 p = *(const float4*)(P + (size_t)ks * BH + i);
        s.x += p.x; s.y += p.y; s.z += p.z; s.w += p.w;
    }
    float4 o;
    o.x = tanhf(s.x); o.y = tanhf(s.y); o.z = tanhf(s.z); o.w = tanhf(s.w);
    *(float4*)(XH + i) = o;
}

// t=0: h0 = 0 -> buf[0] = tanh(buf[0])
__global__ __launch_bounds__(256)
void tanh_inplace(float* __restrict__ X)
{
    int i = (blockIdx.x * 256 + threadIdx.x) * 4;
    float4 x = *(float4*)(X + i);
    float4 o;
    o.x = tanhf(x.x); o.y = tanhf(x.y); o.z = tanhf(x.z); o.w = tanhf(x.w);
    *(float4*)(X + i) = o;
}

// =====================  W_dense pre-pass: transpose + cvt bf16 ==============
// Wd [1024 k][512 n] fp32  ->  WdT [512 n][1024 k] bf16
__global__ __launch_bounds__(256)
void cvt_wdense(const float* __restrict__ Wd, unsigned short* __restrict__ WdT)
{
    __shared__ float tile[64][65];
    const int tid = threadIdx.x;
    const int kt = blockIdx.x * 64, nt = blockIdx.y * 64;
    const int kr = tid >> 2, nc = (tid & 3) * 16;
#pragma unroll
    for (int i = 0; i < 4; ++i) {
        float4 v = *(const float4*)(Wd + (size_t)(kt + kr) * V_SZ + nt + nc + i * 4);
        tile[kr][nc + i * 4 + 0] = v.x;
        tile[kr][nc + i * 4 + 1] = v.y;
        tile[kr][nc + i * 4 + 2] = v.z;
        tile[kr][nc + i * 4 + 3] = v.w;
    }
    __syncthreads();
    const int nr = tid >> 2, kc = (tid & 3) * 16;
    unsigned words[8];
#pragma unroll
    for (int j = 0; j < 8; ++j) {
        unsigned short lo = bf16_rne(tile[kc + 2 * j][nr]);
        unsigned short hi = bf16_rne(tile[kc + 2 * j + 1][nr]);
        words[j] = (unsigned)lo | ((unsigned)hi << 16);
    }
    unsigned* wp = (unsigned*)(WdT + (size_t)(nt + nr) * H_SZ + kt + kc);
    ((uint4*)wp)[0] = make_uint4(words[0], words[1], words[2], words[3]);
    ((uint4*)wp)[1] = make_uint4(words[4], words[5], words[6], words[7]);
}

// =====================  Phase 3: bf16 MFMA GEMM 128x128 tile ================
// out[M1 x V] = hs[M1 x H] @ WdT^T + bias ; A cvt fp32->bf16 (truncate) in
// staging; B pre-transposed bf16 [n][k].
__global__ __launch_bounds__(256, 2)
void gemm_out_mfma(const float* __restrict__ hs, const unsigned short* __restrict__ WdT,
                   const float* __restrict__ bias, float* __restrict__ out)
{
    __shared__ __align__(16) short As[128 * 40];  // [row][k], stride 40 shorts
    __shared__ __align__(16) short Bs[128 * 32];  // [n][k]
    const int tid = threadIdx.x;
    const int lane = tid & 63;
    const int w = tid >> 6;
    const int r0 = blockIdx.y * 128, c0 = blockIdx.x * 128;
    const int rw = (w >> 1) * 64, cw = (w & 1) * 64;

    const int s_row = tid & 127;          // A loader row
    const int s_kh  = tid >> 7;           // A loader k-half (16 floats)
    const int b_n   = tid >> 2;           // B loader n-row (0..63, +64)
    const int b_q   = tid & 3;            // B loader 16B quarter

    f32x4 acc[4][4];
#pragma unroll
    for (int i = 0; i < 4; ++i)
#pragma unroll
        for (int j = 0; j < 4; ++j)
            acc[i][j] = (f32x4){0.f, 0.f, 0.f, 0.f};

    const int l15 = lane & 15, l16 = lane >> 4;

    for (int kc = 0; kc < H_SZ; kc += 32) {
        // ---- A: 16 fp32 -> 16 bf16 (truncate via v_perm), 2x ds_write_b128
        const float* ap = hs + (size_t)(r0 + s_row) * H_SZ + kc + s_kh * 16;
        float4 a0 = ((const float4*)ap)[0];
        float4 a1 = ((const float4*)ap)[1];
        float4 a2 = ((const float4*)ap)[2];
        float4 a3 = ((const float4*)ap)[3];
        unsigned pk[8];
        pk[0] = __builtin_amdgcn_perm(__float_as_uint(a0.y), __float_as_uint(a0.x), 0x07060302u);
        pk[1] = __builtin_amdgcn_perm(__float_as_uint(a0.w), __float_as_uint(a0.z), 0x07060302u);
        pk[2] = __builtin_amdgcn_perm(__float_as_uint(a1.y), __float_as_uint(a1.x), 0x07060302u);
        pk[3] = __builtin_amdgcn_perm(__float_as_uint(a1.w), __float_as_uint(a1.z), 0x07060302u);
        pk[4] = __builtin_amdgcn_perm(__float_as_uint(a2.y), __float_as_uint(a2.x), 0x07060302u);
        pk[5] = __builtin_amdgcn_perm(__float_as_uint(a2.w), __float_as_uint(a2.z), 0x07060302u);
        pk[6] = __builtin_amdgcn_perm(__float_as_uint(a3.y), __float_as_uint(a3.x), 0x07060302u);
        pk[7] = __builtin_amdgcn_perm(__float_as_uint(a3.w), __float_as_uint(a3.z), 0x07060302u);
        // ---- B: two 16B bf16 loads
        bf16x8 bld0 = *(const bf16x8*)(WdT + (size_t)(c0 + b_n) * H_SZ + kc + b_q * 8);
        bf16x8 bld1 = *(const bf16x8*)(WdT + (size_t)(c0 + b_n + 64) * H_SZ + kc + b_q * 8);
        __syncthreads();
        ((uint4*)&As[s_row * 40 + s_kh * 16])[0] = make_uint4(pk[0], pk[1], pk[2], pk[3]);
        ((uint4*)&As[s_row * 40 + s_kh * 16 + 8])[0] = make_uint4(pk[4], pk[5], pk[6], pk[7]);
        *(bf16x8*)(&Bs[b_n * 32 + b_q * 8]) = bld0;
        *(bf16x8*)(&Bs[(b_n + 64) * 32 + b_q * 8]) = bld1;
        __syncthreads();

        bf16x8 af[4], bf[4];
#pragma unroll
        for (int mi = 0; mi < 4; ++mi)
            af[mi] = *(const bf16x8*)(&As[(rw + mi * 16 + l15) * 40 + l16 * 8]);
#pragma unroll
        for (int ni = 0; ni < 4; ++ni)
            bf[ni] = *(const bf16x8*)(&Bs[(cw + ni * 16 + l15) * 32 + l16 * 8]);
#pragma unroll
        for (int mi = 0; mi < 4; ++mi)
#pragma unroll
            for (int ni = 0; ni < 4; ++ni)
                acc[mi][ni] = __builtin_amdgcn_mfma_f32_16x16x32_bf16(
                    af[mi], bf[ni], acc[mi][ni], 0, 0, 0);
    }

    // epilogue: C/D layout col = lane&15, row = (lane>>4)*4 + reg
#pragma unroll
    for (int ni = 0; ni < 4; ++ni) {
        const int col = c0 + cw + ni * 16 + l15;
        const float bv = bias[col];
#pragma unroll
        for (int mi = 0; mi < 4; ++mi) {
            const int rowb = r0 + rw + mi * 16 + l16 * 4;
#pragma unroll
            for (int r = 0; r < 4; ++r)
                out[(size_t)(rowb + r) * V_SZ + col] = acc[mi][ni][r] + bv;
        }
    }
}

// final state copy
__global__ __launch_bounds__(256)
void copy_f4(const float* __restrict__ src, float* __restrict__ dst)
{
    int i = blockIdx.x * 256 + threadIdx.x;
    ((float4*)dst)[i] = ((const float4*)src)[i];
}

extern "C" void kernel_launch(void* const* d_in, const int* in_sizes, int n_in,
                              void* d_out, int out_size, void* d_ws, size_t ws_size,
                              hipStream_t stream)
{
    const float* inputs  = (const float*)d_in[0];
    const float* W_xh    = (const float*)d_in[1];
    const float* W_hh    = (const float*)d_in[2];
    const float* b_h     = (const float*)d_in[3];
    const float* W_dense = (const float*)d_in[4];
    const float* b_dense = (const float*)d_in[5];
    float* out = (float*)d_out;

    float* buf = (float*)d_ws;                         // 256 MB: xh -> hs in place
    float* P   = out;                                  // 8 MB K-split partials
    unsigned short* WdT = (unsigned short*)(out + (size_t)M1 * V_SZ); // 1 MB tail

    // W_dense -> WdT (bf16, transposed) in the out-tail scratch region
    cvt_wdense<<<dim3(H_SZ / 64, V_SZ / 64), 256, 0, stream>>>(W_dense, WdT);

    // Phase 1: xh = inputs @ W_xh + b_h
    gemm_f32_xh<<<dim3(H_SZ / 128, M1 / 128), 256, 0, stream>>>(
        inputs, W_xh, b_h, buf);

    // t = 0
    tanh_inplace<<<dim3(BH / 1024), 256, 0, stream>>>(buf);

    // Phase 2: scan
    for (int t = 1; t < T_STEPS; ++t) {
        scan_gemm<<<dim3(8, 4, 8), 512, 0, stream>>>(
            buf + (size_t)(t - 1) * BH, W_hh, P);
        scan_reduce<<<dim3(BH / 1024), 256, 0, stream>>>(P, buf + (size_t)t * BH);
    }

    // Phase 3: outputs = hs @ W_dense + b_dense (bf16 MFMA)
    gemm_out_mfma<<<dim3(V_SZ / 128, M1 / 128), 256, 0, stream>>>(
        buf, WdT, b_dense, out);

    // final state (overwrites the WdT scratch tail)
    copy_f4<<<dim3(BH / 1024), 256, 0, stream>>>(
        buf + (size_t)(T_STEPS - 1) * BH, out + (size_t)M1 * V_SZ);
}